// Round 4
// baseline (317.489 us; speedup 1.0000x reference)
//
#include <hip/hip_runtime.h>

typedef __attribute__((ext_vector_type(8))) short s8v;   // 8 x bf16 (4 VGPRs)
typedef __attribute__((ext_vector_type(4))) float f4v;   // MFMA accumulator
typedef unsigned short u16;
typedef unsigned long long u64;

#define DM 512
#define NH 8
#define HD 64
#define BB 4
#define NN 2048

__device__ __forceinline__ float bf2f(u16 x){ return __uint_as_float(((unsigned)x)<<16); }
__device__ __forceinline__ u16 f2bf(float f){
  unsigned u = __float_as_uint(f);
  u += 0x7FFFu + ((u>>16)&1u);            // round-to-nearest-even
  return (u16)(u>>16);
}
// async global->LDS, 16B per lane; LDS dest = wave-uniform base + lane*16
__device__ __forceinline__ void gl2lds16(const u16* g, u16* l){
  __builtin_amdgcn_global_load_lds((__attribute__((address_space(1))) void*)(g),
                                   (__attribute__((address_space(3))) void*)(l), 16, 0, 0);
}

// ---------------------------------------------------------------------------
// Kernel 1: permute + bf16-convert weights/biases (f32 inputs).
// ---------------------------------------------------------------------------
__global__ void k_permute(const float* Wq, const float* bq, const float* Wk, const float* bk,
                          const float* Wv, const float* bv, const float* Wm,
                          u16* Wp, u16* Wmp, float* bp){
  int blk = blockIdx.x, tid = threadIdx.x;
  if (blk < 1536){
    int t = blk >> 9, op = blk & 511;
    int srow = ((op & 63) << 3) | (op >> 6);
    const float* W = (t==0) ? Wq : ((t==1) ? Wk : Wv);
    for (int j = tid; j < 512; j += 256)
      Wp[((size_t)t*512 + op)*512 + j] = f2bf(W[(size_t)srow*512 + j]);
  } else if (blk < 2048){
    int o = blk - 1536;
    for (int c = tid; c < 512; c += 256){
      int scol = ((c & 63) << 3) | (c >> 6);
      Wmp[(size_t)o*512 + c] = f2bf(Wm[(size_t)o*512 + scol]);
    }
  } else {
    for (int idx = tid; idx < 1536; idx += 256){
      int t = idx >> 9, op = idx & 511;
      const float* bs = (t==0) ? bq : ((t==1) ? bk : bv);
      int srow = ((op & 63) << 3) | (op >> 6);
      bp[idx] = bs[srow];
    }
  }
}

// ---------------------------------------------------------------------------
// Kernel 2: transpose + convert inputs  f32 [b][i][r] -> bf16 XT[t][b][r][i]
// ---------------------------------------------------------------------------
__global__ __launch_bounds__(256) void k_transpose(const float* q, const float* k, const float* v, u16* XT){
  __shared__ u16 T[64*72];
  int blk = blockIdx.x, tid = threadIdx.x;
  int rt = blk & 31; blk >>= 5;
  int it = blk & 7;  blk >>= 3;
  int b  = blk & 3;  int t = blk >> 2;
  const float* src = (t==0) ? q : ((t==1) ? k : v);
  src += (size_t)b*DM*NN;
  int i0 = it*64, r0 = rt*64;
  int il = tid>>4, rj = (tid&15)*4;
  #pragma unroll
  for (int p=0;p<4;p++){
    int i = il + p*16;
    float4 vv = *(const float4*)&src[(size_t)(i0+i)*NN + r0 + rj];
    float fv[4] = {vv.x, vv.y, vv.z, vv.w};
    #pragma unroll
    for (int qq=0;qq<4;qq++){
      int r = rj + qq;
      int sr = ((r&3)<<4) | (r>>2);
      T[sr*72 + i] = f2bf(fv[qq]);
    }
  }
  __syncthreads();
  u16* dst = XT + ((size_t)(t*4+b)*NN)*DM;
  int rl = tid>>3, ib = (tid&7)*8;
  #pragma unroll
  for (int p=0;p<2;p++){
    int r = rl + p*32;
    int sr = ((r&3)<<4) | (r>>2);
    s8v vv = *(s8v*)&T[sr*72 + ib];
    *(s8v*)&dst[(size_t)(r0+r)*DM + i0 + ib] = vv;
  }
}

// ---------------------------------------------------------------------------
// Kernel 3: projection GEMM, m97-style 128x128 tile, BK=32, global_load_lds.
// A = XT rows (t,b,r), B = Wp rows (o').  C[r][o'].
// t=0 (Q, scaled 1/8) / t=1 (K) -> P[t*4+b][h][r][d];  t=2 (V) -> VT[b][h][d][m].
// LDS K-seg XOR swizzle: slot(r,s) holds global seg s^((r>>1)&3) -> 2-way max.
// ---------------------------------------------------------------------------
__global__ __launch_bounds__(256) void k_proj(const u16* XT, const u16* Wp, const float* bp,
                                              u16* P, u16* VT){
  __shared__ u16 Al[128*32];
  __shared__ u16 Bl[128*32];
  __shared__ u16 S[128*72];
  int blk = blockIdx.x, tid = threadIdx.x;
  int nt = blk & 3; int mt = blk >> 2;      // 192 M-tiles
  int tb = mt >> 4;                         // t*4+b
  int t  = tb >> 2, b = tb & 3;
  int r0 = (mt & 15)*128, o0 = nt*128;
  const u16* Abase = XT + ((size_t)tb*NN + r0)*DM;
  const u16* Bbase = Wp + ((size_t)t*512 + o0)*DM;

  int w = tid>>6, L = tid&63, li = L&15, lq = L>>4;
  int wr = w>>1, wc = w&1;
  // staging decomposition: slot = tid + c*256; r=slot>>2, s=slot&3
  int srow = tid>>2;                         // + c*64
  int g8   = ((tid&3) ^ ((tid>>3)&3))*8;     // swizzled k-seg (elems)
  u16* AldsW = &Al[((tid&192))*8];           // wave-uniform base, +c*256*8
  u16* BldsW = &Bl[((tid&192))*8];
  int sw = (li>>1)&3;                        // fragment-read swizzle

  f4v acc[4][4];
  #pragma unroll
  for (int a=0;a<4;a++)
    #pragma unroll
    for (int c2=0;c2<4;c2++) acc[a][c2] = (f4v){0.f,0.f,0.f,0.f};

  for (int kk=0; kk<16; kk++){
    int k0 = kk*32;
    __syncthreads();
    #pragma unroll
    for (int c=0;c<2;c++){
      gl2lds16(&Abase[(size_t)(srow + c*64)*DM + k0 + g8], AldsW + c*2048);
      gl2lds16(&Bbase[(size_t)(srow + c*64)*DM + k0 + g8], BldsW + c*2048);
    }
    __syncthreads();
    s8v af[4], bfr[4];
    #pragma unroll
    for (int a=0;a<4;a++){
      int r = wr*64 + a*16 + li;
      af[a] = *(s8v*)&Al[r*32 + ((lq ^ sw))*8];
    }
    #pragma unroll
    for (int c2=0;c2<4;c2++){
      int r = wc*64 + c2*16 + li;
      bfr[c2] = *(s8v*)&Bl[r*32 + ((lq ^ sw))*8];
    }
    #pragma unroll
    for (int a=0;a<4;a++)
      #pragma unroll
      for (int c2=0;c2<4;c2++)
        acc[a][c2] = __builtin_amdgcn_mfma_f32_16x16x32_bf16(af[a], bfr[c2], acc[a][c2], 0, 0, 0);
  }

  if (t < 2){
    float scale = (t==0) ? 0.125f : 1.0f;
    #pragma unroll
    for (int c2=0;c2<4;c2++){
      int col = wc*64 + c2*16 + li;
      int h = (o0 + col) >> 6, d = col & 63;
      float bias = bp[t*512 + o0 + col];
      u16* Pb = P + (((size_t)tb*NH + h)*NN)*HD + d;
      #pragma unroll
      for (int a=0;a<4;a++){
        #pragma unroll
        for (int ri=0;ri<4;ri++){
          int row = r0 + wr*64 + a*16 + lq*4 + ri;
          Pb[(size_t)row*HD] = f2bf((acc[a][c2][ri] + bias)*scale);
        }
      }
    }
  } else {
    // V: transpose epilogue, 2 passes of 64 cols (one head each)
    #pragma unroll
    for (int p=0;p<2;p++){
      if (wc == p){
        #pragma unroll
        for (int c2=0;c2<4;c2++){
          int cl = c2*16 + li;
          float bias = bp[2*512 + o0 + p*64 + cl];
          #pragma unroll
          for (int a=0;a<4;a++)
            #pragma unroll
            for (int ri=0;ri<4;ri++)
              S[(wr*64 + a*16 + lq*4 + ri)*72 + cl] = f2bf(acc[a][c2][ri] + bias);
        }
      }
      __syncthreads();
      int dl = tid & 63;
      u16* Vb = VT + (((size_t)b*NH + (o0>>6) + p)*HD + dl)*NN + r0;
      #pragma unroll
      for (int it2=0; it2<4; it2++){
        int mseg = (tid>>6) + it2*4;
        s8v vv; u16* vp = (u16*)&vv;
        #pragma unroll
        for (int j=0;j<8;j++) vp[j] = S[(mseg*8+j)*72 + dl];
        *(s8v*)&Vb[mseg*8] = vv;
      }
      __syncthreads();
    }
  }
}

// ---------------------------------------------------------------------------
// Kernel 4: bit-pack mask. allowed iff M==1.
// ---------------------------------------------------------------------------
__global__ void k_maskpack(const int* M, u64* bits){
  int tid = threadIdx.x;
  size_t word = (size_t)blockIdx.x*4 + (tid>>6);
  int lane = tid & 63;
  int v = M[word*64 + lane];
  u64 bal = __ballot(v == 1);
  if (lane == 0) bits[word] = bal;
}

// ---------------------------------------------------------------------------
// Kernel 4b: per-(b,ntile,mtile) AND of mask words -> fast-path flags.
// ---------------------------------------------------------------------------
__global__ __launch_bounds__(256) void k_maskand(const u64* bits, u64* allw){
  __shared__ u64 red[256];
  int bnt = blockIdx.x, tid = threadIdx.x;
  int mt = tid & 31, rg = tid >> 5;
  const u64* base = bits + (size_t)bnt*64*32;
  u64 v = ~0ull;
  #pragma unroll
  for (int j=0;j<8;j++) v &= base[(size_t)(rg*8+j)*32 + mt];
  red[tid] = v;
  __syncthreads();
  if (tid < 32){
    u64 a = red[tid];
    #pragma unroll
    for (int g2=1; g2<8; g2++) a &= red[g2*32 + tid];
    allw[(size_t)bnt*32 + tid] = a;
  }
}

// ---------------------------------------------------------------------------
// Kernel 5: flash attention per (b,h,n-tile of 64). Unnormalized exp-accum,
// row sums via MFMA with all-ones B (consistent with bf16 P -> bias cancels),
// wave-uniform mask fast path (skips mask loads + cndmasks when tile all-1).
// ---------------------------------------------------------------------------
__global__ __launch_bounds__(256) void k_flash(const u16* P, const u16* VT, const u64* bits,
                                               const u64* allw, u16* Xout){
  __shared__ u16 Ql[64*72];
  __shared__ u16 Kl[64*72];
  __shared__ u16 Vt[64*72];
  __shared__ u16 Pl[64*72];
  int blk = blockIdx.x, tid = threadIdx.x;
  int nt = blk & 31; int bh = blk >> 5;
  int b = bh >> 3;
  int n0 = nt*64;
  const size_t TSZ = (size_t)BB*NH*NN*HD;
  const u16* Qb = P + ((size_t)bh*NN + n0)*HD;
  const u16* Kb = P + TSZ + (size_t)bh*NN*HD;
  const u16* Vb = VT + (size_t)bh*HD*NN;          // [d][m]
  const u64* awp = allw + ((size_t)b*32 + nt)*32;

  int sm = tid>>3, sd = (tid&7)*8;
  int w = tid>>6, L = tid&63, li = L&15, lq = L>>4;
  int sli = ((li&3)<<2) | (li>>2);                 // sigma(li)

  #pragma unroll
  for (int p=0;p<2;p++)
    *(s8v*)&Ql[(sm+p*32)*72 + sd] = *(const s8v*)&Qb[(size_t)(sm+p*32)*HD + sd];

  s8v ones;
  #pragma unroll
  for (int j=0;j<8;j++) ((u16*)&ones)[j] = 0x3F80;   // bf16 1.0

  f4v O[4], RS;
  RS = (f4v){0.f,0.f,0.f,0.f};
  #pragma unroll
  for (int j=0;j<4;j++) O[j] = (f4v){0.f,0.f,0.f,0.f};

  for (int mt=0; mt<32; mt++){
    int m0 = mt*64;
    u64 aw = awp[mt];
    bool fast = (aw == ~0ull);
    // prefetch tiles to registers (overlaps barrier wait)
    s8v kreg[2], vreg[2];
    #pragma unroll
    for (int p=0;p<2;p++){
      kreg[p] = *(const s8v*)&Kb[(size_t)(m0+sm+p*32)*HD + sd];
      vreg[p] = *(const s8v*)&Vb[(size_t)(sm+p*32)*NN + m0 + sd];
    }
    __syncthreads();   // prev iter's PV readers done with Kl/Vt
    #pragma unroll
    for (int p=0;p<2;p++){
      *(s8v*)&Kl[(sm+p*32)*72 + sd] = kreg[p];
      *(s8v*)&Vt[(sm+p*32)*72 + sd] = vreg[p];
    }
    __syncthreads();   // tiles visible

    // S = Q K^T   (Q pre-scaled by 1/8 in projection)
    s8v a0 = *(s8v*)&Ql[(w*16+li)*72 + lq*8];
    s8v a1 = *(s8v*)&Ql[(w*16+li)*72 + 32 + lq*8];
    f4v S[4];
    #pragma unroll
    for (int j=0;j<4;j++){
      s8v b0 = *(s8v*)&Kl[(j*16+li)*72 + lq*8];
      s8v b1 = *(s8v*)&Kl[(j*16+li)*72 + 32 + lq*8];
      f4v c = (f4v){0.f,0.f,0.f,0.f};
      c = __builtin_amdgcn_mfma_f32_16x16x32_bf16(a0, b0, c, 0, 0, 0);
      c = __builtin_amdgcn_mfma_f32_16x16x32_bf16(a1, b1, c, 0, 0, 0);
      S[j] = c;
    }

    // p = exp(s) (masked on slow path), store bf16 (RN) to Pl
    if (fast){
      #pragma unroll
      for (int ri=0;ri<4;ri++){
        int srow = (w*16 + ((ri&3)<<2) + lq)*72;   // sigma(lq*4+ri)
        #pragma unroll
        for (int j=0;j<4;j++){
          unsigned u = __float_as_uint(__expf(S[j][ri])) + 0x8000u;
          Pl[srow + j*16 + li] = (u16)(u>>16);
        }
      }
    } else {
      u64 mw[4];
      #pragma unroll
      for (int ri=0;ri<4;ri++)
        mw[ri] = bits[((size_t)b*NN + n0 + w*16 + lq*4 + ri)*32 + mt];
      #pragma unroll
      for (int ri=0;ri<4;ri++){
        int srow = (w*16 + ((ri&3)<<2) + lq)*72;
        #pragma unroll
        for (int j=0;j<4;j++){
          float e = __expf(S[j][ri]);
          e = ((mw[ri]>>(j*16+li)) & 1ull) ? e : 0.f;
          unsigned u = __float_as_uint(e) + 0x8000u;
          Pl[srow + j*16 + li] = (u16)(u>>16);
        }
      }
    }

    // O += P V ; RS += P * ones  (Pl rows wave-private; DS in-order per wave)
    s8v ap0 = *(s8v*)&Pl[(w*16+sli)*72 + lq*8];
    s8v ap1 = *(s8v*)&Pl[(w*16+sli)*72 + 32 + lq*8];
    RS = __builtin_amdgcn_mfma_f32_16x16x32_bf16(ap0, ones, RS, 0, 0, 0);
    RS = __builtin_amdgcn_mfma_f32_16x16x32_bf16(ap1, ones, RS, 0, 0, 0);
    #pragma unroll
    for (int j2=0;j2<4;j2++){
      s8v b0 = *(s8v*)&Vt[(j2*16+li)*72 + lq*8];
      s8v b1 = *(s8v*)&Vt[(j2*16+li)*72 + 32 + lq*8];
      O[j2] = __builtin_amdgcn_mfma_f32_16x16x32_bf16(ap0, b0, O[j2], 0, 0, 0);
      O[j2] = __builtin_amdgcn_mfma_f32_16x16x32_bf16(ap1, b1, O[j2], 0, 0, 0);
    }
  }

  float inv[4];
  #pragma unroll
  for (int ri=0;ri<4;ri++) inv[ri] = (RS[ri] > 0.f) ? 1.0f/RS[ri] : 0.f;
  int h = bh & 7;
  u16* Xo = Xout + ((size_t)b*NN)*DM + h*HD;
  #pragma unroll
  for (int j2=0;j2<4;j2++){
    int d = j2*16 + li;
    #pragma unroll
    for (int ri=0;ri<4;ri++){
      int n = n0 + w*16 + lq*4 + ri;
      Xo[(size_t)n*DM + d] = f2bf(O[j2][ri]*inv[ri]);
    }
  }
}

// ---------------------------------------------------------------------------
// Kernel 6: output GEMM, 128x128 m97-style. A=Wmp (o rows), B=Xout (n rows).
// out[b][o][n] = acc + bm[o]  (f32)
// ---------------------------------------------------------------------------
__global__ __launch_bounds__(256) void k_out(const u16* Wmp, const u16* Xout, const float* bm, float* out){
  __shared__ u16 Al[128*32];
  __shared__ u16 Bl[128*32];
  int blk = blockIdx.x, tid = threadIdx.x;
  int nt = blk & 15; blk >>= 4;
  int ot = blk & 3;  int b = blk >> 2;
  int o0 = ot*128, n0 = nt*128;
  const u16* Abase = Wmp + (size_t)o0*DM;
  const u16* Bbase = Xout + ((size_t)b*NN + n0)*DM;

  int w = tid>>6, L = tid&63, li = L&15, lq = L>>4;
  int wr = w>>1, wc = w&1;
  int srow = tid>>2;
  int g8   = ((tid&3) ^ ((tid>>3)&3))*8;
  u16* AldsW = &Al[((tid&192))*8];
  u16* BldsW = &Bl[((tid&192))*8];
  int sw = (li>>1)&3;

  f4v acc[4][4];
  #pragma unroll
  for (int a=0;a<4;a++)
    #pragma unroll
    for (int c2=0;c2<4;c2++) acc[a][c2] = (f4v){0.f,0.f,0.f,0.f};

  for (int kk=0; kk<16; kk++){
    int k0 = kk*32;
    __syncthreads();
    #pragma unroll
    for (int c=0;c<2;c++){
      gl2lds16(&Abase[(size_t)(srow + c*64)*DM + k0 + g8], AldsW + c*2048);
      gl2lds16(&Bbase[(size_t)(srow + c*64)*DM + k0 + g8], BldsW + c*2048);
    }
    __syncthreads();
    s8v af[4], bfr[4];
    #pragma unroll
    for (int a=0;a<4;a++){
      int r = wr*64 + a*16 + li;
      af[a] = *(s8v*)&Al[r*32 + ((lq ^ sw))*8];
    }
    #pragma unroll
    for (int c2=0;c2<4;c2++){
      int r = wc*64 + c2*16 + li;
      bfr[c2] = *(s8v*)&Bl[r*32 + ((lq ^ sw))*8];
    }
    #pragma unroll
    for (int a=0;a<4;a++)
      #pragma unroll
      for (int c2=0;c2<4;c2++)
        acc[a][c2] = __builtin_amdgcn_mfma_f32_16x16x32_bf16(af[a], bfr[c2], acc[a][c2], 0, 0, 0);
  }

  #pragma unroll
  for (int a=0;a<4;a++){
    #pragma unroll
    for (int ri=0;ri<4;ri++){
      int o = o0 + wr*64 + a*16 + lq*4 + ri;
      float bias = bm[o];
      float* ob = out + ((size_t)b*DM + o)*NN + n0 + wc*64;
      #pragma unroll
      for (int c2=0;c2<4;c2++)
        ob[c2*16 + li] = acc[a][c2][ri] + bias;
    }
  }
}

// ---------------------------------------------------------------------------
extern "C" void kernel_launch(void* const* d_in, const int* in_sizes, int n_in,
                              void* d_out, int out_size, void* d_ws, size_t ws_size,
                              hipStream_t stream){
  const float* q  = (const float*)d_in[0];
  const float* k  = (const float*)d_in[1];
  const float* v  = (const float*)d_in[2];
  const int*   M  = (const int*)d_in[3];
  const float* Wq = (const float*)d_in[4];
  const float* bq = (const float*)d_in[5];
  const float* Wk = (const float*)d_in[6];
  const float* bk = (const float*)d_in[7];
  const float* Wv = (const float*)d_in[8];
  const float* bv = (const float*)d_in[9];
  const float* Wm = (const float*)d_in[10];
  const float* bm = (const float*)d_in[11];

  char* ws = (char*)d_ws;
  u16*   XT   = (u16*)(ws + 0);            // 25,165,824
  u16*   P    = (u16*)(ws + 25165824);     // Q,K: 16,777,216
  u16*   VT   = (u16*)(ws + 41943040);     //  8,388,608
  u16*   Wp   = (u16*)(ws + 50331648);     //  1,572,864
  u16*   Wmp  = (u16*)(ws + 51904512);     //    524,288
  float* bp   = (float*)(ws + 52428800);   //      6,144
  u64*   bits = (u64*)(ws + 52434944);     //  2,097,152
  u16*   Xout = (u16*)(ws + 54532096);     //  8,388,608
  u64*   allw = (u64*)(ws + 62920704);     //     32,768
  float* out  = (float*)d_out;

  k_permute<<<2049, 256, 0, stream>>>(Wq, bq, Wk, bk, Wv, bv, Wm, Wp, Wmp, bp);
  k_transpose<<<3072, 256, 0, stream>>>(q, k, v, XT);
  k_proj<<<768, 256, 0, stream>>>(XT, Wp, bp, P, VT);
  k_maskpack<<<65536, 256, 0, stream>>>(M, bits);
  k_maskand<<<128, 256, 0, stream>>>(bits, allw);
  k_flash<<<1024, 256, 0, stream>>>(P, VT, bits, allw, Xout);
  k_out<<<256, 256, 0, stream>>>(Wmp, Xout, bm, out);
}

// Round 5
// 299.223 us; speedup vs baseline: 1.0610x; 1.0610x over previous
//
#include <hip/hip_runtime.h>

typedef __attribute__((ext_vector_type(8))) short s8v;   // 8 x bf16 (4 VGPRs)
typedef __attribute__((ext_vector_type(4))) float f4v;   // MFMA accumulator
typedef _Float16 h4 __attribute__((ext_vector_type(4))); // 4 x f16 (2 VGPRs)
typedef unsigned short u16;
typedef unsigned long long u64;

#define DM 512
#define NH 8
#define HD 64
#define BB 4
#define NN 2048

__device__ __forceinline__ float bf2f(u16 x){ return __uint_as_float(((unsigned)x)<<16); }
__device__ __forceinline__ u16 f2bf(float f){
  unsigned u = __float_as_uint(f);
  u += 0x7FFFu + ((u>>16)&1u);            // round-to-nearest-even
  return (u16)(u>>16);
}
// async global->LDS, 16B per lane; LDS dest = wave-uniform base + lane*16
__device__ __forceinline__ void gl2lds16(const u16* g, u16* l){
  __builtin_amdgcn_global_load_lds((__attribute__((address_space(1))) void*)(g),
                                   (__attribute__((address_space(3))) void*)(l), 16, 0, 0);
}

// ---------------------------------------------------------------------------
// Kernel 1: permute + bf16-convert weights/biases (f32 inputs).
// ---------------------------------------------------------------------------
__global__ void k_permute(const float* Wq, const float* bq, const float* Wk, const float* bk,
                          const float* Wv, const float* bv, const float* Wm,
                          u16* Wp, u16* Wmp, float* bp){
  int blk = blockIdx.x, tid = threadIdx.x;
  if (blk < 1536){
    int t = blk >> 9, op = blk & 511;
    int srow = ((op & 63) << 3) | (op >> 6);
    const float* W = (t==0) ? Wq : ((t==1) ? Wk : Wv);
    for (int j = tid; j < 512; j += 256)
      Wp[((size_t)t*512 + op)*512 + j] = f2bf(W[(size_t)srow*512 + j]);
  } else if (blk < 2048){
    int o = blk - 1536;
    for (int c = tid; c < 512; c += 256){
      int scol = ((c & 63) << 3) | (c >> 6);
      Wmp[(size_t)o*512 + c] = f2bf(Wm[(size_t)o*512 + scol]);
    }
  } else {
    for (int idx = tid; idx < 1536; idx += 256){
      int t = idx >> 9, op = idx & 511;
      const float* bs = (t==0) ? bq : ((t==1) ? bk : bv);
      int srow = ((op & 63) << 3) | (op >> 6);
      bp[idx] = bs[srow];
    }
  }
}

// ---------------------------------------------------------------------------
// Kernel 2: transpose + convert inputs  f32 [b][i][r] -> bf16 XT[t][b][r][i]
// ---------------------------------------------------------------------------
__global__ __launch_bounds__(256) void k_transpose(const float* q, const float* k, const float* v, u16* XT){
  __shared__ u16 T[64*72];
  int blk = blockIdx.x, tid = threadIdx.x;
  int rt = blk & 31; blk >>= 5;
  int it = blk & 7;  blk >>= 3;
  int b  = blk & 3;  int t = blk >> 2;
  const float* src = (t==0) ? q : ((t==1) ? k : v);
  src += (size_t)b*DM*NN;
  int i0 = it*64, r0 = rt*64;
  int il = tid>>4, rj = (tid&15)*4;
  #pragma unroll
  for (int p=0;p<4;p++){
    int i = il + p*16;
    float4 vv = *(const float4*)&src[(size_t)(i0+i)*NN + r0 + rj];
    float fv[4] = {vv.x, vv.y, vv.z, vv.w};
    #pragma unroll
    for (int qq=0;qq<4;qq++){
      int r = rj + qq;
      int sr = ((r&3)<<4) | (r>>2);
      T[sr*72 + i] = f2bf(fv[qq]);
    }
  }
  __syncthreads();
  u16* dst = XT + ((size_t)(t*4+b)*NN)*DM;
  int rl = tid>>3, ib = (tid&7)*8;
  #pragma unroll
  for (int p=0;p<2;p++){
    int r = rl + p*32;
    int sr = ((r&3)<<4) | (r>>2);
    s8v vv = *(s8v*)&T[sr*72 + ib];
    *(s8v*)&dst[(size_t)(r0+r)*DM + i0 + ib] = vv;
  }
}

// ---------------------------------------------------------------------------
// Kernel 3: projection GEMM, m97-style 128x128 tile, BK=32, global_load_lds.
// t=0 (Q, scaled 1/8) / t=1 (K) -> P[t*4+b][h][r][d] bf16
// t=2 (V) -> VT[b][h][d][m]  **f16** (PV MFMA runs in f16)
// ---------------------------------------------------------------------------
__global__ __launch_bounds__(256) void k_proj(const u16* XT, const u16* Wp, const float* bp,
                                              u16* P, u16* VT){
  __shared__ u16 Al[128*32];
  __shared__ u16 Bl[128*32];
  __shared__ u16 S[128*72];
  int blk = blockIdx.x, tid = threadIdx.x;
  int nt = blk & 3; int mt = blk >> 2;      // 192 M-tiles
  int tb = mt >> 4;                         // t*4+b
  int t  = tb >> 2, b = tb & 3;
  int r0 = (mt & 15)*128, o0 = nt*128;
  const u16* Abase = XT + ((size_t)tb*NN + r0)*DM;
  const u16* Bbase = Wp + ((size_t)t*512 + o0)*DM;

  int w = tid>>6, L = tid&63, li = L&15, lq = L>>4;
  int wr = w>>1, wc = w&1;
  int srow = tid>>2;
  int g8   = ((tid&3) ^ ((tid>>3)&3))*8;
  u16* AldsW = &Al[((tid&192))*8];
  u16* BldsW = &Bl[((tid&192))*8];
  int sw = (li>>1)&3;

  f4v acc[4][4];
  #pragma unroll
  for (int a=0;a<4;a++)
    #pragma unroll
    for (int c2=0;c2<4;c2++) acc[a][c2] = (f4v){0.f,0.f,0.f,0.f};

  for (int kk=0; kk<16; kk++){
    int k0 = kk*32;
    __syncthreads();
    #pragma unroll
    for (int c=0;c<2;c++){
      gl2lds16(&Abase[(size_t)(srow + c*64)*DM + k0 + g8], AldsW + c*2048);
      gl2lds16(&Bbase[(size_t)(srow + c*64)*DM + k0 + g8], BldsW + c*2048);
    }
    __syncthreads();
    s8v af[4], bfr[4];
    #pragma unroll
    for (int a=0;a<4;a++){
      int r = wr*64 + a*16 + li;
      af[a] = *(s8v*)&Al[r*32 + ((lq ^ sw))*8];
    }
    #pragma unroll
    for (int c2=0;c2<4;c2++){
      int r = wc*64 + c2*16 + li;
      bfr[c2] = *(s8v*)&Bl[r*32 + ((lq ^ sw))*8];
    }
    #pragma unroll
    for (int a=0;a<4;a++)
      #pragma unroll
      for (int c2=0;c2<4;c2++)
        acc[a][c2] = __builtin_amdgcn_mfma_f32_16x16x32_bf16(af[a], bfr[c2], acc[a][c2], 0, 0, 0);
  }

  if (t < 2){
    float scale = (t==0) ? 0.125f : 1.0f;
    #pragma unroll
    for (int c2=0;c2<4;c2++){
      int col = wc*64 + c2*16 + li;
      int h = (o0 + col) >> 6, d = col & 63;
      float bias = bp[t*512 + o0 + col];
      u16* Pb = P + (((size_t)tb*NH + h)*NN)*HD + d;
      #pragma unroll
      for (int a=0;a<4;a++){
        #pragma unroll
        for (int ri=0;ri<4;ri++){
          int row = r0 + wr*64 + a*16 + lq*4 + ri;
          Pb[(size_t)row*HD] = f2bf((acc[a][c2][ri] + bias)*scale);
        }
      }
    }
  } else {
    // V: transpose epilogue (f16 bits), 2 passes of 64 cols (one head each)
    #pragma unroll
    for (int p=0;p<2;p++){
      if (wc == p){
        #pragma unroll
        for (int c2=0;c2<4;c2++){
          int cl = c2*16 + li;
          float bias = bp[2*512 + o0 + p*64 + cl];
          #pragma unroll
          for (int a=0;a<4;a++)
            #pragma unroll
            for (int ri=0;ri<4;ri++){
              _Float16 hh = (_Float16)(acc[a][c2][ri] + bias);
              S[(wr*64 + a*16 + lq*4 + ri)*72 + cl] = *(const u16*)&hh;
            }
        }
      }
      __syncthreads();
      int dl = tid & 63;
      u16* Vb = VT + (((size_t)b*NH + (o0>>6) + p)*HD + dl)*NN + r0;
      #pragma unroll
      for (int it2=0; it2<4; it2++){
        int mseg = (tid>>6) + it2*4;
        s8v vv; u16* vp = (u16*)&vv;
        #pragma unroll
        for (int j=0;j<8;j++) vp[j] = S[(mseg*8+j)*72 + dl];
        *(s8v*)&Vb[mseg*8] = vv;
      }
      __syncthreads();
    }
  }
}

// ---------------------------------------------------------------------------
// Kernel 4: bit-pack mask. allowed iff M==1.
// ---------------------------------------------------------------------------
__global__ void k_maskpack(const int* M, u64* bits){
  int tid = threadIdx.x;
  size_t word = (size_t)blockIdx.x*4 + (tid>>6);
  int lane = tid & 63;
  int v = M[word*64 + lane];
  u64 bal = __ballot(v == 1);
  if (lane == 0) bits[word] = bal;
}

// ---------------------------------------------------------------------------
// Kernel 4b: per-(b,ntile,mtile) AND of mask words -> fast-path flags.
// ---------------------------------------------------------------------------
__global__ __launch_bounds__(256) void k_maskand(const u64* bits, u64* allw){
  __shared__ u64 red[256];
  int bnt = blockIdx.x, tid = threadIdx.x;
  int mt = tid & 31, rg = tid >> 5;
  const u64* base = bits + (size_t)bnt*64*32;
  u64 v = ~0ull;
  #pragma unroll
  for (int j=0;j<8;j++) v &= base[(size_t)(rg*8+j)*32 + mt];
  red[tid] = v;
  __syncthreads();
  if (tid < 32){
    u64 a = red[tid];
    #pragma unroll
    for (int g2=1; g2<8; g2++) a &= red[g2*32 + tid];
    allw[(size_t)bnt*32 + tid] = a;
  }
}

// ---------------------------------------------------------------------------
// Kernel 5: transposed-S flash attention per (b,h,n-tile 64).
// S^T = K Q^T (Q frags in registers). Wave w owns m-slice [w*16,w*16+16):
// its S^T C-regs ARE the B-fragment of a 16x16x16 f16 MFMA (k=lq*4+r), so
// P feeds PV with zero LDS movement. V^T staged in LDS (f16). O^T partials
// reduced across waves once at the end (LDS reuse of K/V buffers).
// ---------------------------------------------------------------------------
__global__ __launch_bounds__(256) void k_flash(const u16* Pq, const u16* VT, const u64* bits,
                                               const u64* allw, u16* Xout){
  __shared__ __align__(16) char smem[19456];
  u16*   Kl  = (u16*)smem;                 // [64][72] bf16
  u16*   Vl  = (u16*)(smem + 9216);        // [64][72] f16 bits
  float* Red = (float*)smem;               // [64][68] f32, aliases Kl/Vl after loop
  float* lsb = (float*)(smem + 18432);     // [4][64]

  int blk = blockIdx.x, tid = threadIdx.x;
  int nt = blk & 31; int bh = blk >> 5;
  int b = bh >> 3;
  int n0 = nt*64;
  const size_t TSZ = (size_t)BB*NH*NN*HD;
  const u16* Qb = Pq + ((size_t)bh*NN + n0)*HD;
  const u16* Kb = Pq + TSZ + (size_t)bh*NN*HD;
  const u16* Vb = VT + (size_t)bh*HD*NN;          // [d][m] f16
  const u64* awp = allw + ((size_t)b*32 + nt)*32;

  int sm = tid>>3, sd = (tid&7)*8;
  int w = tid>>6, L = tid&63, li = L&15, lq = L>>4;

  // Q fragments in registers (loop-invariant): Qf[j][h2] = Q[n0+j*16+li][h2*32+lq*8..+8]
  s8v Qf[4][2];
  #pragma unroll
  for (int j=0;j<4;j++)
    #pragma unroll
    for (int h2=0;h2<2;h2++)
      Qf[j][h2] = *(const s8v*)&Qb[(size_t)(j*16+li)*HD + h2*32 + lq*8];

  f4v O[4][4];     // O^T partial: [d-block j2][n-block j]
  #pragma unroll
  for (int j2=0;j2<4;j2++)
    #pragma unroll
    for (int j=0;j<4;j++) O[j2][j] = (f4v){0.f,0.f,0.f,0.f};
  float ls[4] = {0.f,0.f,0.f,0.f};

  for (int mt=0; mt<32; mt++){
    int m0 = mt*64;
    u64 aw = awp[mt];
    bool fast = (aw == ~0ull);
    // prefetch K/V tiles to regs (overlaps barrier wait)
    s8v kreg[2], vreg[2];
    #pragma unroll
    for (int p=0;p<2;p++){
      kreg[p] = *(const s8v*)&Kb[(size_t)(m0+sm+p*32)*HD + sd];
      vreg[p] = *(const s8v*)&Vb[(size_t)(sm+p*32)*NN + m0 + sd];
    }
    __syncthreads();
    #pragma unroll
    for (int p=0;p<2;p++){
      *(s8v*)&Kl[(sm+p*32)*72 + sd] = kreg[p];
      *(s8v*)&Vl[(sm+p*32)*72 + sd] = vreg[p];
    }
    __syncthreads();

    // K-frag: wave's own m-slice rows
    s8v Kf0 = *(s8v*)&Kl[(w*16+li)*72 + lq*8];
    s8v Kf1 = *(s8v*)&Kl[(w*16+li)*72 + 32 + lq*8];

    // S^T[m=w-slice][n] = K Q^T : lane holds P[n=j*16+li][m=lq*4+r]
    f4v S[4];
    #pragma unroll
    for (int j=0;j<4;j++){
      f4v c = (f4v){0.f,0.f,0.f,0.f};
      c = __builtin_amdgcn_mfma_f32_16x16x32_bf16(Kf0, Qf[j][0], c, 0, 0, 0);
      c = __builtin_amdgcn_mfma_f32_16x16x32_bf16(Kf1, Qf[j][1], c, 0, 0, 0);
      S[j] = c;
    }

    // exp (+mask), accumulate row partials, pack to f16 B-fragments
    h4 Pf[4];
    if (fast){
      #pragma unroll
      for (int j=0;j<4;j++){
        float e0 = __expf(S[j][0]), e1 = __expf(S[j][1]);
        float e2 = __expf(S[j][2]), e3 = __expf(S[j][3]);
        ls[j] += (e0+e1)+(e2+e3);
        Pf[j][0] = (_Float16)e0; Pf[j][1] = (_Float16)e1;
        Pf[j][2] = (_Float16)e2; Pf[j][3] = (_Float16)e3;
      }
    } else {
      int mbit = w*16 + lq*4;
      #pragma unroll
      for (int j=0;j<4;j++){
        u64 mw = bits[((size_t)b*NN + n0 + j*16 + li)*32 + mt];
        float e[4];
        #pragma unroll
        for (int r=0;r<4;r++){
          float ev = __expf(S[j][r]);
          e[r] = ((mw>>(mbit+r)) & 1ull) ? ev : 0.f;
          Pf[j][r] = (_Float16)e[r];
        }
        ls[j] += (e[0]+e[1])+(e[2]+e[3]);
      }
    }

    // O^T += V^T P : A = V^T-frag (wave's m-slice), B = Pf (in regs)
    #pragma unroll
    for (int j2=0;j2<4;j2++){
      h4 Vf = *(h4*)&Vl[(j2*16+li)*72 + w*16 + lq*4];
      #pragma unroll
      for (int j=0;j<4;j++)
        O[j2][j] = __builtin_amdgcn_mfma_f32_16x16x16f16(Vf, Pf[j], O[j2][j], 0, 0, 0);
    }
  }

  // reduce ls over lq (lanes li, li+16, li+32, li+48)
  #pragma unroll
  for (int j=0;j<4;j++){
    float r = ls[j];
    r += __shfl_xor(r, 16); r += __shfl_xor(r, 32);
    ls[j] = r;
  }
  if (lq == 0){
    #pragma unroll
    for (int j=0;j<4;j++) lsb[w*64 + j*16 + li] = ls[j];
  }
  __syncthreads();     // all waves done with Kl/Vl; lsb visible

  // cross-wave O^T reduction into Red[n][d] (4 phases)
  #pragma unroll
  for (int ph=0; ph<4; ph++){
    if (w == ph){
      #pragma unroll
      for (int j=0;j<4;j++)
        #pragma unroll
        for (int j2=0;j2<4;j2++){
          f4v* p = (f4v*)&Red[(j*16+li)*68 + j2*16 + lq*4];
          if (ph == 0) *p = O[j2][j];
          else { f4v t = *p; t += O[j2][j]; *p = t; }
        }
    }
    __syncthreads();
  }

  // normalize + write Xout[b][n][h*64+d]
  int n = tid>>2, d0 = (tid&3)*16;
  float s = lsb[n] + lsb[64+n] + lsb[128+n] + lsb[192+n];
  float inv = (s > 0.f) ? 1.0f/s : 0.f;
  int h = bh & 7;
  u16* Xo = Xout + ((size_t)b*NN + n0 + n)*DM + h*HD + d0;
  u16 tmp[16];
  #pragma unroll
  for (int e2=0;e2<4;e2++){
    f4v vv = *(f4v*)&Red[n*68 + d0 + e2*4];
    #pragma unroll
    for (int q2=0;q2<4;q2++) tmp[e2*4+q2] = f2bf(vv[q2]*inv);
  }
  *(s8v*)&Xo[0] = *(s8v*)&tmp[0];
  *(s8v*)&Xo[8] = *(s8v*)&tmp[8];
}

// ---------------------------------------------------------------------------
// Kernel 6: output GEMM, 128x128 m97-style. A=Wmp (o rows), B=Xout (n rows).
// ---------------------------------------------------------------------------
__global__ __launch_bounds__(256) void k_out(const u16* Wmp, const u16* Xout, const float* bm, float* out){
  __shared__ u16 Al[128*32];
  __shared__ u16 Bl[128*32];
  int blk = blockIdx.x, tid = threadIdx.x;
  int nt = blk & 15; blk >>= 4;
  int ot = blk & 3;  int b = blk >> 2;
  int o0 = ot*128, n0 = nt*128;
  const u16* Abase = Wmp + (size_t)o0*DM;
  const u16* Bbase = Xout + ((size_t)b*NN + n0)*DM;

  int w = tid>>6, L = tid&63, li = L&15, lq = L>>4;
  int wr = w>>1, wc = w&1;
  int srow = tid>>2;
  int g8   = ((tid&3) ^ ((tid>>3)&3))*8;
  u16* AldsW = &Al[((tid&192))*8];
  u16* BldsW = &Bl[((tid&192))*8];
  int sw = (li>>1)&3;

  f4v acc[4][4];
  #pragma unroll
  for (int a=0;a<4;a++)
    #pragma unroll
    for (int c2=0;c2<4;c2++) acc[a][c2] = (f4v){0.f,0.f,0.f,0.f};

  for (int kk=0; kk<16; kk++){
    int k0 = kk*32;
    __syncthreads();
    #pragma unroll
    for (int c=0;c<2;c++){
      gl2lds16(&Abase[(size_t)(srow + c*64)*DM + k0 + g8], AldsW + c*2048);
      gl2lds16(&Bbase[(size_t)(srow + c*64)*DM + k0 + g8], BldsW + c*2048);
    }
    __syncthreads();
    s8v af[4], bfr[4];
    #pragma unroll
    for (int a=0;a<4;a++){
      int r = wr*64 + a*16 + li;
      af[a] = *(s8v*)&Al[r*32 + ((lq ^ sw))*8];
    }
    #pragma unroll
    for (int c2=0;c2<4;c2++){
      int r = wc*64 + c2*16 + li;
      bfr[c2] = *(s8v*)&Bl[r*32 + ((lq ^ sw))*8];
    }
    #pragma unroll
    for (int a=0;a<4;a++)
      #pragma unroll
      for (int c2=0;c2<4;c2++)
        acc[a][c2] = __builtin_amdgcn_mfma_f32_16x16x32_bf16(af[a], bfr[c2], acc[a][c2], 0, 0, 0);
  }

  #pragma unroll
  for (int a=0;a<4;a++){
    #pragma unroll
    for (int ri=0;ri<4;ri++){
      int o = o0 + wr*64 + a*16 + lq*4 + ri;
      float bias = bm[o];
      float* ob = out + ((size_t)b*DM + o)*NN + n0 + wc*64;
      #pragma unroll
      for (int c2=0;c2<4;c2++)
        ob[c2*16 + li] = acc[a][c2][ri] + bias;
    }
  }
}

// ---------------------------------------------------------------------------
extern "C" void kernel_launch(void* const* d_in, const int* in_sizes, int n_in,
                              void* d_out, int out_size, void* d_ws, size_t ws_size,
                              hipStream_t stream){
  const float* q  = (const float*)d_in[0];
  const float* k  = (const float*)d_in[1];
  const float* v  = (const float*)d_in[2];
  const int*   M  = (const int*)d_in[3];
  const float* Wq = (const float*)d_in[4];
  const float* bq = (const float*)d_in[5];
  const float* Wk = (const float*)d_in[6];
  const float* bk = (const float*)d_in[7];
  const float* Wv = (const float*)d_in[8];
  const float* bv = (const float*)d_in[9];
  const float* Wm = (const float*)d_in[10];
  const float* bm = (const float*)d_in[11];

  char* ws = (char*)d_ws;
  u16*   XT   = (u16*)(ws + 0);            // 25,165,824
  u16*   P    = (u16*)(ws + 25165824);     // Q,K: 16,777,216
  u16*   VT   = (u16*)(ws + 41943040);     //  8,388,608 (f16)
  u16*   Wp   = (u16*)(ws + 50331648);     //  1,572,864
  u16*   Wmp  = (u16*)(ws + 51904512);     //    524,288
  float* bp   = (float*)(ws + 52428800);   //      6,144
  u64*   bits = (u64*)(ws + 52434944);     //  2,097,152
  u16*   Xout = (u16*)(ws + 54532096);     //  8,388,608
  u64*   allw = (u64*)(ws + 62920704);     //     32,768
  float* out  = (float*)d_out;

  k_permute<<<2049, 256, 0, stream>>>(Wq, bq, Wk, bk, Wv, bv, Wm, Wp, Wmp, bp);
  k_transpose<<<3072, 256, 0, stream>>>(q, k, v, XT);
  k_proj<<<768, 256, 0, stream>>>(XT, Wp, bp, P, VT);
  k_maskpack<<<65536, 256, 0, stream>>>(M, bits);
  k_maskand<<<128, 256, 0, stream>>>(bits, allw);
  k_flash<<<1024, 256, 0, stream>>>(P, VT, bits, allw, Xout);
  k_out<<<256, 256, 0, stream>>>(Wmp, Xout, bm, out);
}